// Round 6
// baseline (250.224 us; speedup 1.0000x reference)
//
#include <hip/hip_runtime.h>
#include <stdint.h>
#include <stddef.h>

// Multi-head attention: x@w_qkv+b -> heads -> softmax(QK^T/sqrt(D))V -> @w_proj+b
// B=8 N=1024 C=1024 H=16 D=64. bf16 MFMA, fp32 accum, fp32 softmax (log2 domain).
// GEMM1 (QKV): 256x256 8-phase counted-vmcnt schedule (T2+T3+T4+T5).
// Attention: 32x32x16 swapped-operand MFMA + in-register P redistribution.

#define DEVI __device__ __forceinline__

typedef float f32x4 __attribute__((ext_vector_type(4)));
typedef float f32x16 __attribute__((ext_vector_type(16)));
typedef __bf16 bf16x8 __attribute__((ext_vector_type(8)));
typedef unsigned short u16x8 __attribute__((ext_vector_type(8)));
typedef unsigned short u16x4 __attribute__((ext_vector_type(4)));
typedef unsigned int u32;
typedef unsigned int u32x4 __attribute__((ext_vector_type(4)));

static constexpr int M1 = 8192;   // B*N rows

DEVI unsigned short f2bf(float f) {
  uint32_t u = __builtin_bit_cast(uint32_t, f);
  u += 0x7FFFu + ((u >> 16) & 1u);   // RNE
  return (unsigned short)(u >> 16);
}

DEVI float fexp2(float x) {
  float r;
  asm("v_exp_f32 %0, %1" : "=v"(r) : "v"(x));
  return r;
}

DEVI u32 cvtpk(float lo, float hi) {
  u32 r;
  asm("v_cvt_pk_bf16_f32 %0, %1, %2" : "=v"(r) : "v"(lo), "v"(hi));
  return r;
}

DEVI void plswap(u32& a, u32& b) {
  asm("v_permlane32_swap_b32 %0, %1" : "+v"(a), "+v"(b));
}

DEVI void gll16(const unsigned short* g, unsigned short* lds) {
  __builtin_amdgcn_global_load_lds(
      (const __attribute__((address_space(1))) void*)g,
      (__attribute__((address_space(3))) void*)lds, 16, 0, 0);
}

DEVI bf16x8 lds_frag(const unsigned short* p) {
  return __builtin_bit_cast(bf16x8, *(const u16x8*)p);
}

// ---------------- convert x fp32 -> bf16 ----------------
__global__ void k_cvt(const float* __restrict__ in, unsigned short* __restrict__ out, int n4) {
  int i = blockIdx.x * blockDim.x + threadIdx.x;
  if (i < n4) {
    float4 v = reinterpret_cast<const float4*>(in)[i];
    u16x4 o = { f2bf(v.x), f2bf(v.y), f2bf(v.z), f2bf(v.w) };
    reinterpret_cast<u16x4*>(out)[i] = o;
  }
}

// ---------------- transpose + convert weights: in[R][C] fp32 -> out[C][R] bf16 ----------------
__global__ void k_tr_cvt(const float* __restrict__ in, unsigned short* __restrict__ out,
                         int R, int Cc) {
  __shared__ float tile[32][33];
  int c0 = blockIdx.x * 32, r0 = blockIdx.y * 32;
  int tx = threadIdx.x, ty = threadIdx.y;   // blockDim (32,8)
#pragma unroll
  for (int j = 0; j < 32; j += 8)
    tile[ty + j][tx] = in[(size_t)(r0 + ty + j) * Cc + c0 + tx];
  __syncthreads();
#pragma unroll
  for (int j = 0; j < 32; j += 8)
    out[(size_t)(c0 + ty + j) * R + r0 + tx] = f2bf(tile[tx][ty + j]);
}

// ---------------- bf16 transpose V[bh][n][64] -> Vt[bh][64][n] ----------------
__global__ void k_tr_v(const unsigned short* __restrict__ in, unsigned short* __restrict__ out) {
  __shared__ unsigned short t[32][33];
  int d0 = blockIdx.x * 32, n0 = blockIdx.y * 32, bh = blockIdx.z;
  const unsigned short* ip = in + (size_t)bh * 1024 * 64;
  unsigned short* op = out + (size_t)bh * 64 * 1024;
  int tx = threadIdx.x, ty = threadIdx.y;   // blockDim (32,8)
#pragma unroll
  for (int j = 0; j < 32; j += 8)
    t[ty + j][tx] = ip[(size_t)(n0 + ty + j) * 64 + d0 + tx];
  __syncthreads();
#pragma unroll
  for (int j = 0; j < 32; j += 8)
    op[(size_t)(d0 + ty + j) * 1024 + n0 + tx] = t[tx][ty + j];
}

// =====================================================================
// GEMM1 (QKV): 256x256 tile, BK=64, 8 waves (2Mx4N), 8-phase-per-2-K-tiles
// schedule with counted vmcnt (never 0 in steady state). K=1024 -> 16 K-tiles.
// LDS: As/Bs = [2 dbuf][256 rows][64 k] bf16, 16B-chunk XOR swizzle c^=(r&7).
// Per group T (4 phases): p1{rd am0+bn0, stage A-h1(T+1)}, p2{rd bn1},
// p3{rd am1, stage B-h0(T+2)}, p4{stage B-h1+A-h0(T+2), vmcnt(6)}.
// Epilogue: +bias, scatter Q(prescaled log2e/8), K, V to [B,H,N,D] bf16.
// =====================================================================
__global__ __launch_bounds__(512, 2)
void k_gemm1(const unsigned short* __restrict__ A,
             const unsigned short* __restrict__ Bt,
             const float* __restrict__ bias,
             unsigned short* __restrict__ Qp,
             unsigned short* __restrict__ Kp,
             unsigned short* __restrict__ Vp) {
  constexpr int K = 1024, NT = K / 64;   // 16 K-tiles
  __shared__ unsigned short As[2 * 256 * 64];   // 64 KB
  __shared__ unsigned short Bs[2 * 256 * 64];   // 64 KB

  const int tid = threadIdx.x;
  const int w = tid >> 6, l = tid & 63;
  const int ln = l & 15, kg = l >> 4;
  const int wr = w >> 2, wc = w & 3;     // 2 x 4 wave grid

  const int bid = blockIdx.x;
  const int swz = (bid & 7) * 48 + (bid >> 3);   // 384 blocks, bijective XCD swizzle
  const int rt = swz & 31, ct = swz >> 5;        // 32 x 12 tiles
  const int row0 = rt * 256, col0 = ct * 256;

  const unsigned short* Ag = A + (size_t)row0 * K;
  const unsigned short* Bg = Bt + (size_t)col0 * K;

  // stage one half-tile (128 rows x 64 k): linear LDS dest, inverse-swizzled source
  auto stageA = [&](int kt, int hf) {
    unsigned short* lb = &As[((kt & 1) * 256 + hf * 128) * 64];
#pragma unroll
    for (int j = 0; j < 2; j++) {
      int idx = j * 512 + tid;
      int r = idx >> 3, c = idx & 7;
      gll16(Ag + (size_t)(hf * 128 + r) * K + kt * 64 + ((c ^ (r & 7)) * 8), lb + idx * 8);
    }
  };
  auto stageB = [&](int kt, int hf) {
    unsigned short* lb = &Bs[((kt & 1) * 256 + hf * 128) * 64];
#pragma unroll
    for (int j = 0; j < 2; j++) {
      int idx = j * 512 + tid;
      int r = idx >> 3, c = idx & 7;
      gll16(Bg + (size_t)(hf * 128 + r) * K + kt * 64 + ((c ^ (r & 7)) * 8), lb + idx * 8);
    }
  };

  f32x4 acc[8][4] = {};
  bf16x8 am[4][2], b0[2][2], b1[2][2];

  // prologue: T0 all 4 halves + T1 {A-h0, B-h0, B-h1}; wait T0 done (6 in flight)
  stageA(0, 0); stageA(0, 1); stageB(0, 0); stageB(0, 1);
  stageA(1, 0); stageB(1, 0); stageB(1, 1);
  asm volatile("s_waitcnt vmcnt(6)" ::: "memory");
  __builtin_amdgcn_s_barrier();

  for (int T = 0; T < NT; T++) {
    const int dbase = (T & 1) * 256 * 64;

    // ---- phase 1: read am0 (8) + bn0 (4); stage A-h1 of T+1 ----
#pragma unroll
    for (int mi = 0; mi < 4; mi++)
#pragma unroll
      for (int kk = 0; kk < 2; kk++) {
        int r = wr * 128 + mi * 16 + ln;
        int c = (kk * 4 + kg) ^ (r & 7);
        am[mi][kk] = lds_frag(&As[dbase + r * 64 + c * 8]);
      }
#pragma unroll
    for (int ni = 0; ni < 2; ni++)
#pragma unroll
      for (int kk = 0; kk < 2; kk++) {
        int r = wc * 64 + ni * 16 + ln;
        int c = (kk * 4 + kg) ^ (r & 7);
        b0[ni][kk] = lds_frag(&Bs[dbase + r * 64 + c * 8]);
      }
    if (T + 1 < NT) stageA(T + 1, 1);
    __builtin_amdgcn_s_barrier();
    asm volatile("s_waitcnt lgkmcnt(0)" ::: "memory");
    __builtin_amdgcn_sched_barrier(0);
    __builtin_amdgcn_s_setprio(1);
#pragma unroll
    for (int mi = 0; mi < 4; mi++)
#pragma unroll
      for (int ni = 0; ni < 2; ni++)
#pragma unroll
        for (int kk = 0; kk < 2; kk++)
          acc[mi][ni] = __builtin_amdgcn_mfma_f32_16x16x32_bf16(am[mi][kk], b0[ni][kk], acc[mi][ni], 0, 0, 0);
    __builtin_amdgcn_s_setprio(0);
    __builtin_amdgcn_s_barrier();

    // ---- phase 2: read bn1 (4) ----
#pragma unroll
    for (int ni = 0; ni < 2; ni++)
#pragma unroll
      for (int kk = 0; kk < 2; kk++) {
        int r = wc * 64 + (2 + ni) * 16 + ln;
        int c = (kk * 4 + kg) ^ (r & 7);
        b1[ni][kk] = lds_frag(&Bs[dbase + r * 64 + c * 8]);
      }
    __builtin_amdgcn_s_barrier();
    asm volatile("s_waitcnt lgkmcnt(0)" ::: "memory");
    __builtin_amdgcn_sched_barrier(0);
    __builtin_amdgcn_s_setprio(1);
#pragma unroll
    for (int mi = 0; mi < 4; mi++)
#pragma unroll
      for (int ni = 0; ni < 2; ni++)
#pragma unroll
        for (int kk = 0; kk < 2; kk++)
          acc[mi][2 + ni] = __builtin_amdgcn_mfma_f32_16x16x32_bf16(am[mi][kk], b1[ni][kk], acc[mi][2 + ni], 0, 0, 0);
    __builtin_amdgcn_s_setprio(0);
    __builtin_amdgcn_s_barrier();

    // ---- phase 3: read am1 (8); stage B-h0 of T+2 ----
#pragma unroll
    for (int mi = 0; mi < 4; mi++)
#pragma unroll
      for (int kk = 0; kk < 2; kk++) {
        int r = wr * 128 + (4 + mi) * 16 + ln;
        int c = (kk * 4 + kg) ^ (r & 7);
        am[mi][kk] = lds_frag(&As[dbase + r * 64 + c * 8]);
      }
    if (T + 2 < NT) stageB(T + 2, 0);
    __builtin_amdgcn_s_barrier();
    asm volatile("s_waitcnt lgkmcnt(0)" ::: "memory");
    __builtin_amdgcn_sched_barrier(0);
    __builtin_amdgcn_s_setprio(1);
#pragma unroll
    for (int mi = 0; mi < 4; mi++)
#pragma unroll
      for (int ni = 0; ni < 2; ni++)
#pragma unroll
        for (int kk = 0; kk < 2; kk++)
          acc[4 + mi][2 + ni] = __builtin_amdgcn_mfma_f32_16x16x32_bf16(am[mi][kk], b1[ni][kk], acc[4 + mi][2 + ni], 0, 0, 0);
    __builtin_amdgcn_s_setprio(0);
    __builtin_amdgcn_s_barrier();

    // ---- phase 4: stage B-h1 + A-h0 of T+2; MFMA am1 x bn0; counted vmcnt ----
    if (T + 2 < NT) { stageB(T + 2, 1); stageA(T + 2, 0); }
    __builtin_amdgcn_s_barrier();
    __builtin_amdgcn_s_setprio(1);
#pragma unroll
    for (int mi = 0; mi < 4; mi++)
#pragma unroll
      for (int ni = 0; ni < 2; ni++)
#pragma unroll
        for (int kk = 0; kk < 2; kk++)
          acc[4 + mi][ni] = __builtin_amdgcn_mfma_f32_16x16x32_bf16(am[mi][kk], b0[ni][kk], acc[4 + mi][ni], 0, 0, 0);
    __builtin_amdgcn_s_setprio(0);
    if (T + 2 < NT)      asm volatile("s_waitcnt vmcnt(6)" ::: "memory");
    else if (T + 1 < NT) asm volatile("s_waitcnt vmcnt(0)" ::: "memory");
    __builtin_amdgcn_s_barrier();
  }

  // ---- epilogue: +bias, scatter to Q (prescaled), K, V [B,H,N,D] ----
  constexpr float QS = 0.18033688011112042f;   // log2(e)/8
  const int three = col0 >> 10;
  const int hh = ((col0 & 1023) >> 6) + wc;
  unsigned short* tgt = (three == 0) ? Qp : (three == 1) ? Kp : Vp;
  const float sc = (three == 0) ? QS : 1.f;
  float bv[4];
#pragma unroll
  for (int n = 0; n < 4; n++) bv[n] = bias[col0 + wc * 64 + n * 16 + ln];
#pragma unroll
  for (int m = 0; m < 8; m++)
#pragma unroll
    for (int r = 0; r < 4; r++) {
      int row = row0 + wr * 128 + m * 16 + kg * 4 + r;
      int bb = row >> 10, nn = row & 1023;
      size_t base = ((size_t)(bb * 16 + hh) * 1024 + nn) * 64;
#pragma unroll
      for (int n = 0; n < 4; n++)
        tgt[base + n * 16 + ln] = f2bf((acc[m][n][r] + bv[n]) * sc);
    }
}

// ---------------- GEMM (128x128 m97-structure, kept for projection) ----------------
template <int EPI, int NCOLS>
__global__ __launch_bounds__(256, 2)
void k_gemm(const unsigned short* __restrict__ A,
            const unsigned short* __restrict__ Bt,
            const float* __restrict__ bias,
            float* __restrict__ Out) {
  constexpr int K = 1024, NK = K / 32;
  __shared__ unsigned short As[2][128 * 32];
  __shared__ unsigned short Bs[2][128 * 32];

  const int tid = threadIdx.x;
  const int w = tid >> 6, l = tid & 63;
  const int ln = l & 15, kg = l >> 4;
  const int wr = w >> 1, wc = w & 1;

  const int rt = blockIdx.x % (M1 / 128);
  const int ct = blockIdx.x / (M1 / 128);
  const int row0 = rt * 128, col0 = ct * 128;

  f32x4 acc[4][4] = {};

  const unsigned short* Ag = A + (size_t)row0 * K;
  const unsigned short* Bg = Bt + (size_t)col0 * K;

  auto stage = [&](int buf, int kt) {
    const unsigned short* ga = Ag + kt * 32;
    const unsigned short* gb = Bg + kt * 32;
#pragma unroll
    for (int j = 0; j < 2; j++) {
      int c = j * 256 + w * 64 + l;
      int r = c >> 2, s = c & 3;
      int ss = s ^ ((r >> 1) & 3);
      gll16(ga + (size_t)r * K + ss * 8, &As[buf][(j * 256 + w * 64) * 8]);
      gll16(gb + (size_t)r * K + ss * 8, &Bs[buf][(j * 256 + w * 64) * 8]);
    }
  };

  stage(0, 0);
  __syncthreads();

  int buf = 0;
  for (int kt = 0; kt < NK; kt++) {
    if (kt + 1 < NK) stage(buf ^ 1, kt + 1);

    bf16x8 af[4], bfr[4];
#pragma unroll
    for (int m = 0; m < 4; m++) {
      int r = wr * 64 + m * 16 + ln;
      int sl = kg ^ ((r >> 1) & 3);
      af[m] = lds_frag(&As[buf][r * 32 + sl * 8]);
    }
#pragma unroll
    for (int n = 0; n < 4; n++) {
      int r = wc * 64 + n * 16 + ln;
      int sl = kg ^ ((r >> 1) & 3);
      bfr[n] = lds_frag(&Bs[buf][r * 32 + sl * 8]);
    }
    __builtin_amdgcn_s_setprio(1);
#pragma unroll
    for (int m = 0; m < 4; m++)
#pragma unroll
      for (int n = 0; n < 4; n++)
        acc[m][n] = __builtin_amdgcn_mfma_f32_16x16x32_bf16(af[m], bfr[n], acc[m][n], 0, 0, 0);
    __builtin_amdgcn_s_setprio(0);

    __syncthreads();
    buf ^= 1;
  }

  float bv[4];
#pragma unroll
  for (int n = 0; n < 4; n++) bv[n] = bias[col0 + wc * 64 + n * 16 + ln];
#pragma unroll
  for (int m = 0; m < 4; m++)
#pragma unroll
    for (int r = 0; r < 4; r++) {
      int row = row0 + wr * 64 + m * 16 + kg * 4 + r;
#pragma unroll
      for (int n = 0; n < 4; n++)
        Out[(size_t)row * 1024 + col0 + wc * 64 + n * 16 + ln] = acc[m][n][r] + bv[n];
    }
}

// ---------------- flash attention, 32x32x16 swapped MFMA ----------------
__global__ __launch_bounds__(256, 4)
void k_attn(const unsigned short* __restrict__ Qg, const unsigned short* __restrict__ Kg,
            const unsigned short* __restrict__ Vtg, unsigned short* __restrict__ AO) {
  __shared__ unsigned short Ks[2][64 * 64];
  __shared__ unsigned short Vs[2][64 * 64];

  const int tid = threadIdx.x;
  const int w = tid >> 6, l = tid & 63;
  const int lq = l & 31, b = l >> 5;

  const int bh = blockIdx.x;
  const int qt = blockIdx.y;
  const int qbase = qt * 128 + w * 32;

  bf16x8 qf[4];
#pragma unroll
  for (int kk = 0; kk < 4; kk++) {
    size_t off = ((size_t)bh * 1024 + qbase + lq) * 64 + kk * 16 + b * 8;
    qf[kk] = __builtin_bit_cast(bf16x8, *(const u16x8*)(Qg + off));
  }

  f32x16 acc[2] = {};
  float mrun = -1e30f, lrun = 0.f;

  const unsigned short* Kbh = Kg + (size_t)bh * 1024 * 64;
  const unsigned short* Vbh = Vtg + (size_t)bh * 64 * 1024;

  auto stage = [&](int buf, int t) {
#pragma unroll
    for (int j = 0; j < 2; j++) {
      int c = j * 256 + w * 64 + l;
      int r = c >> 3, s = c & 7;
      int ss = s ^ (r & 7);
      gll16(Kbh + (size_t)(t * 64 + r) * 64 + ss * 8, &Ks[buf][(j * 256 + w * 64) * 8]);
      gll16(Vbh + (size_t)r * 1024 + t * 64 + ss * 8, &Vs[buf][(j * 256 + w * 64) * 8]);
    }
  };

  stage(0, 0);
  __syncthreads();

  int buf = 0;
  for (int t = 0; t < 16; t++) {
    if (t + 1 < 16) stage(buf ^ 1, t + 1);

    f32x16 s[2];
    __builtin_amdgcn_s_setprio(1);
#pragma unroll
    for (int kb = 0; kb < 2; kb++) {
      f32x16 z = {};
#pragma unroll
      for (int kk = 0; kk < 4; kk++) {
        int row = kb * 32 + lq;
        int ss = (kk * 2 + b) ^ (row & 7);
        bf16x8 kf = lds_frag(&Ks[buf][row * 64 + ss * 8]);
        z = __builtin_amdgcn_mfma_f32_32x32x16_bf16(kf, qf[kk], z, 0, 0, 0);
      }
      s[kb] = z;
    }
    __builtin_amdgcn_s_setprio(0);

    float tm = s[0][0];
#pragma unroll
    for (int kb = 0; kb < 2; kb++)
#pragma unroll
      for (int r = 0; r < 16; r++) tm = fmaxf(tm, s[kb][r]);
    tm = fmaxf(tm, __shfl_xor(tm, 32));

    if (!__all(tm <= mrun + 8.f)) {
      float mnew = fmaxf(mrun, tm);
      float al = fexp2(mrun - mnew);
      mrun = mnew;
      lrun *= al;
#pragma unroll
      for (int r = 0; r < 16; r++) {
        float aq = __shfl(al, (r & 3) + 8 * (r >> 2) + 4 * b);
        acc[0][r] *= aq;
        acc[1][r] *= aq;
      }
    }

    float rs = 0.f;
#pragma unroll
    for (int kb = 0; kb < 2; kb++)
#pragma unroll
      for (int r = 0; r < 16; r++) {
        float pv = fexp2(s[kb][r] - mrun);
        s[kb][r] = pv;
        rs += pv;
      }
    rs += __shfl_xor(rs, 32);
    lrun += rs;

    bf16x8 pa[4];
#pragma unroll
    for (int kb = 0; kb < 2; kb++) {
      u32 pk[4][2];
#pragma unroll
      for (int t4 = 0; t4 < 4; t4++) {
        pk[t4][0] = cvtpk(s[kb][t4 * 4 + 0], s[kb][t4 * 4 + 1]);
        pk[t4][1] = cvtpk(s[kb][t4 * 4 + 2], s[kb][t4 * 4 + 3]);
      }
#pragma unroll
      for (int sh = 0; sh < 2; sh++) {
        u32 a0 = pk[2 * sh][0], b0 = pk[2 * sh + 1][0];
        plswap(a0, b0);
        u32 a1 = pk[2 * sh][1], b1 = pk[2 * sh + 1][1];
        plswap(a1, b1);
        u32x4 fr = { a0, a1, b0, b1 };
        pa[kb * 2 + sh] = __builtin_bit_cast(bf16x8, fr);
      }
    }

    __builtin_amdgcn_s_setprio(1);
#pragma unroll
    for (int n = 0; n < 2; n++) {
#pragma unroll
      for (int st = 0; st < 4; st++) {
        int row = n * 32 + lq;
        int ss = (st * 2 + b) ^ (row & 7);
        bf16x8 vb = lds_frag(&Vs[buf][row * 64 + ss * 8]);
        acc[n] = __builtin_amdgcn_mfma_f32_32x32x16_bf16(pa[st], vb, acc[n], 0, 0, 0);
      }
    }
    __builtin_amdgcn_s_setprio(0);

    __syncthreads();
    buf ^= 1;
  }

  const int bb = bh >> 4, h = bh & 15;
  float linv = 1.f / lrun;
#pragma unroll
  for (int r = 0; r < 16; r++) {
    float lq_r = __shfl(linv, (r & 3) + 8 * (r >> 2) + 4 * b);
    int row = qbase + (r & 3) + 8 * (r >> 2) + 4 * b;
    size_t base = ((size_t)(bb * 1024 + row)) * 1024 + h * 64;
#pragma unroll
    for (int n = 0; n < 2; n++)
      AO[base + n * 32 + lq] = f2bf(acc[n][r] * lq_r);
  }
}

// ---------------- launch ----------------
extern "C" void kernel_launch(void* const* d_in, const int* in_sizes, int n_in,
                              void* d_out, int out_size, void* d_ws, size_t ws_size,
                              hipStream_t stream) {
  const float* x      = (const float*)d_in[0];
  const float* w_qkv  = (const float*)d_in[1];
  const float* b_qkv  = (const float*)d_in[2];
  const float* w_proj = (const float*)d_in[3];
  const float* b_proj = (const float*)d_in[4];
  float* out = (float*)d_out;

  constexpr size_t SZ_XB  = (size_t)8192 * 1024 * 2;
  constexpr size_t SZ_WQ  = (size_t)3072 * 1024 * 2;
  constexpr size_t SZ_WP  = (size_t)1024 * 1024 * 2;
  constexpr size_t SZ_QKV = (size_t)8 * 16 * 1024 * 64 * 2;
  char* ws = (char*)d_ws;
  unsigned short* xb     = (unsigned short*)(ws);
  unsigned short* wqkvT  = (unsigned short*)(ws + SZ_XB);
  unsigned short* wprojT = (unsigned short*)(ws + SZ_XB + SZ_WQ);
  unsigned short* Qb     = (unsigned short*)(ws + SZ_XB + SZ_WQ + SZ_WP);
  unsigned short* Kb     = (unsigned short*)(ws + SZ_XB + SZ_WQ + SZ_WP + SZ_QKV);
  unsigned short* Vtb    = (unsigned short*)(ws + SZ_XB + SZ_WQ + SZ_WP + 2 * SZ_QKV);
  unsigned short* VrawAO = (unsigned short*)(ws + SZ_XB + SZ_WQ + SZ_WP + 3 * SZ_QKV);
  size_t needed = SZ_XB + SZ_WQ + SZ_WP + 4 * SZ_QKV;
  if (ws_size < needed) return;

  k_cvt<<<8192, 256, 0, stream>>>(x, xb, 8192 * 1024 / 4);
  dim3 tb(32, 8);
  k_tr_cvt<<<dim3(96, 32), tb, 0, stream>>>(w_qkv, wqkvT, 1024, 3072);
  k_tr_cvt<<<dim3(32, 32), tb, 0, stream>>>(w_proj, wprojT, 1024, 1024);
  // QKV GEMM: 256^2 8-phase -> Q(scaled), K, Vraw [B,H,N,D]
  k_gemm1<<<384, 512, 0, stream>>>(xb, wqkvT, b_qkv, Qb, Kb, VrawAO);
  // transpose V -> Vt [B,H,D,N]
  k_tr_v<<<dim3(2, 32, 128), tb, 0, stream>>>(VrawAO, Vtb);
  // flash attention -> AO (aliases Vraw; Vraw dead after k_tr_v)
  k_attn<<<dim3(128, 8), 256, 0, stream>>>(Qb, Kb, Vtb, VrawAO);
  // projection -> out fp32
  k_gemm<2, 1024><<<64 * 8, 256, 0, stream>>>(VrawAO, wprojT, b_proj, out);
}

// Round 7
// 247.623 us; speedup vs baseline: 1.0105x; 1.0105x over previous
//
#include <hip/hip_runtime.h>
#include <stdint.h>
#include <stddef.h>

// Multi-head attention: x@w_qkv+b -> heads -> softmax(QK^T/sqrt(D))V -> @w_proj+b
// B=8 N=1024 C=1024 H=16 D=64. bf16 MFMA, fp32 accum, fp32 softmax (log2 domain).
// GEMM1: 256x256 8-phase counted-vmcnt, L2-aware 2D XCD swizzle.
// Attention: barrier-free; K/V pre-packed fragment-major, read direct from L2.

#define DEVI __device__ __forceinline__

typedef float f32x4 __attribute__((ext_vector_type(4)));
typedef float f32x16 __attribute__((ext_vector_type(16)));
typedef __bf16 bf16x8 __attribute__((ext_vector_type(8)));
typedef unsigned short u16x8 __attribute__((ext_vector_type(8)));
typedef unsigned short u16x4 __attribute__((ext_vector_type(4)));
typedef unsigned int u32;
typedef unsigned int u32x4 __attribute__((ext_vector_type(4)));

static constexpr int M1 = 8192;   // B*N rows

DEVI unsigned short f2bf(float f) {
  uint32_t u = __builtin_bit_cast(uint32_t, f);
  u += 0x7FFFu + ((u >> 16) & 1u);   // RNE
  return (unsigned short)(u >> 16);
}

DEVI float fexp2(float x) {
  float r;
  asm("v_exp_f32 %0, %1" : "=v"(r) : "v"(x));
  return r;
}

DEVI u32 cvtpk(float lo, float hi) {
  u32 r;
  asm("v_cvt_pk_bf16_f32 %0, %1, %2" : "=v"(r) : "v"(lo), "v"(hi));
  return r;
}

DEVI void plswap(u32& a, u32& b) {
  asm("v_permlane32_swap_b32 %0, %1" : "+v"(a), "+v"(b));
}

DEVI void gll16(const unsigned short* g, unsigned short* lds) {
  __builtin_amdgcn_global_load_lds(
      (const __attribute__((address_space(1))) void*)g,
      (__attribute__((address_space(3))) void*)lds, 16, 0, 0);
}

DEVI bf16x8 lds_frag(const unsigned short* p) {
  return __builtin_bit_cast(bf16x8, *(const u16x8*)p);
}

DEVI bf16x8 gfrag(const unsigned short* p) {
  return __builtin_bit_cast(bf16x8, *(const u16x8*)p);
}

// ---------------- convert x fp32 -> bf16 ----------------
__global__ void k_cvt(const float* __restrict__ in, unsigned short* __restrict__ out, int n4) {
  int i = blockIdx.x * blockDim.x + threadIdx.x;
  if (i < n4) {
    float4 v = reinterpret_cast<const float4*>(in)[i];
    u16x4 o = { f2bf(v.x), f2bf(v.y), f2bf(v.z), f2bf(v.w) };
    reinterpret_cast<u16x4*>(out)[i] = o;
  }
}

// ---------------- transpose + convert weights: in[R][C] fp32 -> out[C][R] bf16 ----------------
__global__ void k_tr_cvt(const float* __restrict__ in, unsigned short* __restrict__ out,
                         int R, int Cc) {
  __shared__ float tile[32][33];
  int c0 = blockIdx.x * 32, r0 = blockIdx.y * 32;
  int tx = threadIdx.x, ty = threadIdx.y;   // blockDim (32,8)
#pragma unroll
  for (int j = 0; j < 32; j += 8)
    tile[ty + j][tx] = in[(size_t)(r0 + ty + j) * Cc + c0 + tx];
  __syncthreads();
#pragma unroll
  for (int j = 0; j < 32; j += 8)
    out[(size_t)(c0 + ty + j) * R + r0 + tx] = f2bf(tile[tx][ty + j]);
}

// ---------------- pack K,V into fragment-major blocks ----------------
// Kpk[bh][t][f=kb*4+kk][lane][8] : lane(b*32+lq) <- K[t*64+kb*32+lq][kk*16+b*8+e]
// Vpk[bh][t][f=n*4+st][lane][8]  : lane(b*32+lq) <- V[t*64+(st*2+b)*8+e][n*32+lq]
__global__ __launch_bounds__(256)
void k_pack(const unsigned short* __restrict__ K, const unsigned short* __restrict__ V,
            unsigned short* __restrict__ Kpk, unsigned short* __restrict__ Vpk) {
  __shared__ unsigned short vt[64][80];   // padded rows (160B, 16B-aligned)
  const int t = blockIdx.x, bh = blockIdx.y;
  const int tid = threadIdx.x, l = tid & 63, g = tid >> 6;
  const int lq = l & 31, b = l >> 5;
  const unsigned short* Kt = K + ((size_t)bh * 1024 + t * 64) * 64;
  const unsigned short* Vt = V + ((size_t)bh * 1024 + t * 64) * 64;
  unsigned short* Ko = Kpk + (((size_t)bh * 16 + t) * 8) * 512;
  unsigned short* Vo = Vpk + (((size_t)bh * 16 + t) * 8) * 512;

  // stage V tile into LDS (row-major, coalesced)
#pragma unroll
  for (int j = 0; j < 2; j++) {
    int idx = tid + j * 256;
    int r = idx >> 3, c = (idx & 7) * 8;
    *(u16x8*)&vt[r][c] = *(const u16x8*)&Vt[r * 64 + c];
  }
  // pack K (reads 16B contiguous, L1-hot; writes fully coalesced)
#pragma unroll
  for (int j = 0; j < 2; j++) {
    int f = g * 2 + j, kb = f >> 2, kk = f & 3;
    u16x8 kv = *(const u16x8*)&Kt[(kb * 32 + lq) * 64 + kk * 16 + b * 8];
    *(u16x8*)&Ko[f * 512 + l * 8] = kv;
  }
  __syncthreads();
  // pack V (transpose gather from LDS; writes fully coalesced)
#pragma unroll
  for (int j = 0; j < 2; j++) {
    int f = g * 2 + j, n = f >> 2, st = f & 3;
    u16x8 vv;
#pragma unroll
    for (int e = 0; e < 8; e++) vv[e] = vt[(st * 2 + b) * 8 + e][n * 32 + lq];
    *(u16x8*)&Vo[f * 512 + l * 8] = vv;
  }
}

// =====================================================================
// GEMM1 (QKV): 256x256 tile, BK=64, 8 waves, 8-phase counted-vmcnt.
// XCD-aware 2D swizzle: each XCD owns an 8rt x 6ct sub-grid, rt-minor order
// -> in-flight window ~4MB A + 2MB B (L2-fit).
// =====================================================================
__global__ __launch_bounds__(512, 2)
void k_gemm1(const unsigned short* __restrict__ A,
             const unsigned short* __restrict__ Bt,
             const float* __restrict__ bias,
             unsigned short* __restrict__ Qp,
             unsigned short* __restrict__ Kp,
             unsigned short* __restrict__ Vp) {
  constexpr int K = 1024, NT = K / 64;   // 16 K-tiles
  __shared__ unsigned short As[2 * 256 * 64];   // 64 KB
  __shared__ unsigned short Bs[2 * 256 * 64];   // 64 KB

  const int tid = threadIdx.x;
  const int w = tid >> 6, l = tid & 63;
  const int ln = l & 15, kg = l >> 4;
  const int wr = w >> 2, wc = w & 3;     // 2 x 4 wave grid

  const int bid = blockIdx.x;
  const int xcd = bid & 7, ii = bid >> 3;          // 8 XCDs x 48 tiles
  const int rt = (xcd >> 1) * 8 + (ii & 7);        // 8-row band per XCD pair-half
  const int ct = (xcd & 1) * 6 + (ii >> 3);        // 6-col band
  const int row0 = rt * 256, col0 = ct * 256;

  const unsigned short* Ag = A + (size_t)row0 * K;
  const unsigned short* Bg = Bt + (size_t)col0 * K;

  auto stageA = [&](int kt, int hf) {
    unsigned short* lb = &As[((kt & 1) * 256 + hf * 128) * 64];
#pragma unroll
    for (int j = 0; j < 2; j++) {
      int idx = j * 512 + tid;
      int r = idx >> 3, c = idx & 7;
      gll16(Ag + (size_t)(hf * 128 + r) * K + kt * 64 + ((c ^ (r & 7)) * 8), lb + idx * 8);
    }
  };
  auto stageB = [&](int kt, int hf) {
    unsigned short* lb = &Bs[((kt & 1) * 256 + hf * 128) * 64];
#pragma unroll
    for (int j = 0; j < 2; j++) {
      int idx = j * 512 + tid;
      int r = idx >> 3, c = idx & 7;
      gll16(Bg + (size_t)(hf * 128 + r) * K + kt * 64 + ((c ^ (r & 7)) * 8), lb + idx * 8);
    }
  };

  f32x4 acc[8][4] = {};
  bf16x8 am[4][2], b0[2][2], b1[2][2];

  stageA(0, 0); stageA(0, 1); stageB(0, 0); stageB(0, 1);
  stageA(1, 0); stageB(1, 0); stageB(1, 1);
  asm volatile("s_waitcnt vmcnt(6)" ::: "memory");
  __builtin_amdgcn_s_barrier();

  for (int T = 0; T < NT; T++) {
    const int dbase = (T & 1) * 256 * 64;

    // phase 1: read am0+bn0; stage A-h1(T+1)
#pragma unroll
    for (int mi = 0; mi < 4; mi++)
#pragma unroll
      for (int kk = 0; kk < 2; kk++) {
        int r = wr * 128 + mi * 16 + ln;
        int c = (kk * 4 + kg) ^ (r & 7);
        am[mi][kk] = lds_frag(&As[dbase + r * 64 + c * 8]);
      }
#pragma unroll
    for (int ni = 0; ni < 2; ni++)
#pragma unroll
      for (int kk = 0; kk < 2; kk++) {
        int r = wc * 64 + ni * 16 + ln;
        int c = (kk * 4 + kg) ^ (r & 7);
        b0[ni][kk] = lds_frag(&Bs[dbase + r * 64 + c * 8]);
      }
    if (T + 1 < NT) stageA(T + 1, 1);
    __builtin_amdgcn_s_barrier();
    asm volatile("s_waitcnt lgkmcnt(0)" ::: "memory");
    __builtin_amdgcn_sched_barrier(0);
    __builtin_amdgcn_s_setprio(1);
#pragma unroll
    for (int mi = 0; mi < 4; mi++)
#pragma unroll
      for (int ni = 0; ni < 2; ni++)
#pragma unroll
        for (int kk = 0; kk < 2; kk++)
          acc[mi][ni] = __builtin_amdgcn_mfma_f32_16x16x32_bf16(am[mi][kk], b0[ni][kk], acc[mi][ni], 0, 0, 0);
    __builtin_amdgcn_s_setprio(0);
    __builtin_amdgcn_s_barrier();

    // phase 2: read bn1
#pragma unroll
    for (int ni = 0; ni < 2; ni++)
#pragma unroll
      for (int kk = 0; kk < 2; kk++) {
        int r = wc * 64 + (2 + ni) * 16 + ln;
        int c = (kk * 4 + kg) ^ (r & 7);
        b1[ni][kk] = lds_frag(&Bs[dbase + r * 64 + c * 8]);
      }
    __builtin_amdgcn_s_barrier();
    asm volatile("s_waitcnt lgkmcnt(0)" ::: "memory");
    __builtin_amdgcn_sched_barrier(0);
    __builtin_amdgcn_s_setprio(1);
#pragma unroll
    for (int mi = 0; mi < 4; mi++)
#pragma unroll
      for (int ni = 0; ni < 2; ni++)
#pragma unroll
        for (int kk = 0; kk < 2; kk++)
          acc[mi][2 + ni] = __builtin_amdgcn_mfma_f32_16x16x32_bf16(am[mi][kk], b1[ni][kk], acc[mi][2 + ni], 0, 0, 0);
    __builtin_amdgcn_s_setprio(0);
    __builtin_amdgcn_s_barrier();

    // phase 3: read am1; stage B-h0(T+2)
#pragma unroll
    for (int mi = 0; mi < 4; mi++)
#pragma unroll
      for (int kk = 0; kk < 2; kk++) {
        int r = wr * 128 + (4 + mi) * 16 + ln;
        int c = (kk * 4 + kg) ^ (r & 7);
        am[mi][kk] = lds_frag(&As[dbase + r * 64 + c * 8]);
      }
    if (T + 2 < NT) stageB(T + 2, 0);
    __builtin_amdgcn_s_barrier();
    asm volatile("s_waitcnt lgkmcnt(0)" ::: "memory");
    __builtin_amdgcn_sched_barrier(0);
    __builtin_amdgcn_s_setprio(1);
#pragma unroll
    for (int mi = 0; mi < 4; mi++)
#pragma unroll
      for (int ni = 0; ni < 2; ni++)
#pragma unroll
        for (int kk = 0; kk < 2; kk++)
          acc[4 + mi][2 + ni] = __builtin_amdgcn_mfma_f32_16x16x32_bf16(am[mi][kk], b1[ni][kk], acc[4 + mi][2 + ni], 0, 0, 0);
    __builtin_amdgcn_s_setprio(0);
    __builtin_amdgcn_s_barrier();

    // phase 4: stage B-h1 + A-h0 (T+2); MFMA am1 x bn0; counted vmcnt
    if (T + 2 < NT) { stageB(T + 2, 1); stageA(T + 2, 0); }
    __builtin_amdgcn_s_barrier();
    __builtin_amdgcn_s_setprio(1);
#pragma unroll
    for (int mi = 0; mi < 4; mi++)
#pragma unroll
      for (int ni = 0; ni < 2; ni++)
#pragma unroll
        for (int kk = 0; kk < 2; kk++)
          acc[4 + mi][ni] = __builtin_amdgcn_mfma_f32_16x16x32_bf16(am[mi][kk], b0[ni][kk], acc[4 + mi][ni], 0, 0, 0);
    __builtin_amdgcn_s_setprio(0);
    if (T + 2 < NT)      asm volatile("s_waitcnt vmcnt(6)" ::: "memory");
    else if (T + 1 < NT) asm volatile("s_waitcnt vmcnt(0)" ::: "memory");
    __builtin_amdgcn_s_barrier();
  }

  constexpr float QS = 0.18033688011112042f;   // log2(e)/8
  const int three = col0 >> 10;
  const int hh = ((col0 & 1023) >> 6) + wc;
  unsigned short* tgt = (three == 0) ? Qp : (three == 1) ? Kp : Vp;
  const float sc = (three == 0) ? QS : 1.f;
  float bv[4];
#pragma unroll
  for (int n = 0; n < 4; n++) bv[n] = bias[col0 + wc * 64 + n * 16 + ln];
#pragma unroll
  for (int m = 0; m < 8; m++)
#pragma unroll
    for (int r = 0; r < 4; r++) {
      int row = row0 + wr * 128 + m * 16 + kg * 4 + r;
      int bb = row >> 10, nn = row & 1023;
      size_t base = ((size_t)(bb * 16 + hh) * 1024 + nn) * 64;
#pragma unroll
      for (int n = 0; n < 4; n++)
        tgt[base + n * 16 + ln] = f2bf((acc[m][n][r] + bv[n]) * sc);
    }
}

// ---------------- GEMM (128x128 m97-structure, projection) ----------------
template <int EPI, int NCOLS>
__global__ __launch_bounds__(256, 2)
void k_gemm(const unsigned short* __restrict__ A,
            const unsigned short* __restrict__ Bt,
            const float* __restrict__ bias,
            float* __restrict__ Out) {
  constexpr int K = 1024, NK = K / 32;
  __shared__ unsigned short As[2][128 * 32];
  __shared__ unsigned short Bs[2][128 * 32];

  const int tid = threadIdx.x;
  const int w = tid >> 6, l = tid & 63;
  const int ln = l & 15, kg = l >> 4;
  const int wr = w >> 1, wc = w & 1;

  const int rt = blockIdx.x % (M1 / 128);
  const int ct = blockIdx.x / (M1 / 128);
  const int row0 = rt * 128, col0 = ct * 128;

  f32x4 acc[4][4] = {};

  const unsigned short* Ag = A + (size_t)row0 * K;
  const unsigned short* Bg = Bt + (size_t)col0 * K;

  auto stage = [&](int buf, int kt) {
    const unsigned short* ga = Ag + kt * 32;
    const unsigned short* gb = Bg + kt * 32;
#pragma unroll
    for (int j = 0; j < 2; j++) {
      int c = j * 256 + w * 64 + l;
      int r = c >> 2, s = c & 3;
      int ss = s ^ ((r >> 1) & 3);
      gll16(ga + (size_t)r * K + ss * 8, &As[buf][(j * 256 + w * 64) * 8]);
      gll16(gb + (size_t)r * K + ss * 8, &Bs[buf][(j * 256 + w * 64) * 8]);
    }
  };

  stage(0, 0);
  __syncthreads();

  int buf = 0;
  for (int kt = 0; kt < NK; kt++) {
    if (kt + 1 < NK) stage(buf ^ 1, kt + 1);

    bf16x8 af[4], bfr[4];
#pragma unroll
    for (int m = 0; m < 4; m++) {
      int r = wr * 64 + m * 16 + ln;
      int sl = kg ^ ((r >> 1) & 3);
      af[m] = lds_frag(&As[buf][r * 32 + sl * 8]);
    }
#pragma unroll
    for (int n = 0; n < 4; n++) {
      int r = wc * 64 + n * 16 + ln;
      int sl = kg ^ ((r >> 1) & 3);
      bfr[n] = lds_frag(&Bs[buf][r * 32 + sl * 8]);
    }
    __builtin_amdgcn_s_setprio(1);
#pragma unroll
    for (int m = 0; m < 4; m++)
#pragma unroll
      for (int n = 0; n < 4; n++)
        acc[m][n] = __builtin_amdgcn_mfma_f32_16x16x32_bf16(af[m], bfr[n], acc[m][n], 0, 0, 0);
    __builtin_amdgcn_s_setprio(0);

    __syncthreads();
    buf ^= 1;
  }

  float bv[4];
#pragma unroll
  for (int n = 0; n < 4; n++) bv[n] = bias[col0 + wc * 64 + n * 16 + ln];
#pragma unroll
  for (int m = 0; m < 4; m++)
#pragma unroll
    for (int r = 0; r < 4; r++) {
      int row = row0 + wr * 64 + m * 16 + kg * 4 + r;
#pragma unroll
      for (int n = 0; n < 4; n++)
        Out[(size_t)row * 1024 + col0 + wc * 64 + n * 16 + ln] = acc[m][n][r] + bv[n];
    }
}

// ---------------- flash attention: barrier-free, packed direct reads ----------------
// grid (128 bh, 8 qt); 4 waves x 32 q-rows, KVBLK=64; no LDS, no __syncthreads.
__global__ __launch_bounds__(256, 4)
void k_attn(const unsigned short* __restrict__ Qg, const unsigned short* __restrict__ Kpk,
            const unsigned short* __restrict__ Vpk, unsigned short* __restrict__ AO) {
  const int tid = threadIdx.x;
  const int w = tid >> 6, l = tid & 63;
  const int lq = l & 31, b = l >> 5;

  const int bh = blockIdx.x;
  const int qt = blockIdx.y;
  const int qbase = qt * 128 + w * 32;

  bf16x8 qf[4];
#pragma unroll
  for (int kk = 0; kk < 4; kk++) {
    size_t off = ((size_t)bh * 1024 + qbase + lq) * 64 + kk * 16 + b * 8;
    qf[kk] = gfrag(Qg + off);
  }

  f32x16 acc[2] = {};
  float mrun = -1e30f, lrun = 0.f;

  const unsigned short* Kp = Kpk + (size_t)bh * 16 * 8 * 512;
  const unsigned short* Vp = Vpk + (size_t)bh * 16 * 8 * 512;

#pragma unroll 1
  for (int t = 0; t < 16; t++) {
    const unsigned short* Kt = Kp + (size_t)t * 8 * 512 + l * 8;
    const unsigned short* Vt = Vp + (size_t)t * 8 * 512 + l * 8;

    // ---- S^T = K Q^T (fragments direct from packed global, L2-hit) ----
    f32x16 s[2];
    __builtin_amdgcn_s_setprio(1);
#pragma unroll
    for (int kb = 0; kb < 2; kb++) {
      f32x16 z = {};
#pragma unroll
      for (int kk = 0; kk < 4; kk++) {
        bf16x8 kf = gfrag(Kt + (kb * 4 + kk) * 512);
        z = __builtin_amdgcn_mfma_f32_32x32x16_bf16(kf, qf[kk], z, 0, 0, 0);
      }
      s[kb] = z;
    }
    __builtin_amdgcn_s_setprio(0);

    // ---- softmax (log2 domain), lane-local q = lq ----
    float tm = s[0][0];
#pragma unroll
    for (int kb = 0; kb < 2; kb++)
#pragma unroll
      for (int r = 0; r < 16; r++) tm = fmaxf(tm, s[kb][r]);
    tm = fmaxf(tm, __shfl_xor(tm, 32));

    if (!__all(tm <= mrun + 8.f)) {
      float mnew = fmaxf(mrun, tm);
      float al = fexp2(mrun - mnew);
      mrun = mnew;
      lrun *= al;
#pragma unroll
      for (int r = 0; r < 16; r++) {
        float aq = __shfl(al, (r & 3) + 8 * (r >> 2) + 4 * b);
        acc[0][r] *= aq;
        acc[1][r] *= aq;
      }
    }

    float rs = 0.f;
#pragma unroll
    for (int kb = 0; kb < 2; kb++)
#pragma unroll
      for (int r = 0; r < 16; r++) {
        float pv = fexp2(s[kb][r] - mrun);
        s[kb][r] = pv;
        rs += pv;
      }
    rs += __shfl_xor(rs, 32);
    lrun += rs;

    // ---- P -> A-operand frags (in-register cvt_pk + permlane32_swap) ----
    bf16x8 pa[4];
#pragma unroll
    for (int kb = 0; kb < 2; kb++) {
      u32 pk[4][2];
#pragma unroll
      for (int t4 = 0; t4 < 4; t4++) {
        pk[t4][0] = cvtpk(s[kb][t4 * 4 + 0], s[kb][t4 * 4 + 1]);
        pk[t4][1] = cvtpk(s[kb][t4 * 4 + 2], s[kb][t4 * 4 + 3]);
      }
#pragma unroll
      for (int sh = 0; sh < 2; sh++) {
        u32 a0 = pk[2 * sh][0], b0 = pk[2 * sh + 1][0];
        plswap(a0, b0);
        u32 a1 = pk[2 * sh][1], b1 = pk[2 * sh + 1][1];
        plswap(a1, b1);
        u32x4 fr = { a0, a1, b0, b1 };
        pa[kb * 2 + sh] = __builtin_bit_cast(bf16x8, fr);
      }
    }

    // ---- O += P V ----
    __builtin_amdgcn_s_setprio(1);
#pragma unroll
    for (int n = 0; n < 2; n++) {
#pragma unroll
      for (int st = 0; st < 4; st++) {
        bf16x8 vb = gfrag(Vt + (n * 4 + st) * 512);
        acc[n] = __builtin_amdgcn_mfma_f32_32x32x16_bf16(pa[st], vb, acc[n], 0, 0, 0);
      }
    }
    __builtin_amdgcn_s_setprio(0);
  }

  const int bb = bh >> 4, h = bh & 15;
  float linv = 1.f / lrun;
#pragma unroll
  for (int r = 0; r < 16; r++) {
    float lq_r = __shfl(linv, (r & 3) + 8 * (r >> 2) + 4 * b);
    int row = qbase + (r & 3) + 8 * (r >> 2) + 4 * b;
    size_t base = ((size_t)(bb * 1024 + row)) * 1024 + h * 64;
#pragma unroll
    for (int n = 0; n < 2; n++)
      AO[base + n * 32 + lq] = f2bf(acc[n][r] * lq_r);
  }
}

// ---------------- launch ----------------
extern "C" void kernel_launch(void* const* d_in, const int* in_sizes, int n_in,
                              void* d_out, int out_size, void* d_ws, size_t ws_size,
                              hipStream_t stream) {
  const float* x      = (const float*)d_in[0];
  const float* w_qkv  = (const float*)d_in[1];
  const float* b_qkv  = (const float*)d_in[2];
  const float* w_proj = (const float*)d_in[3];
  const float* b_proj = (const float*)d_in[4];
  float* out = (float*)d_out;

  constexpr size_t SZ_XB  = (size_t)8192 * 1024 * 2;         // 16.78 MB
  constexpr size_t SZ_WQ  = (size_t)3072 * 1024 * 2;
  constexpr size_t SZ_WP  = (size_t)1024 * 1024 * 2;
  constexpr size_t SZ_QKV = (size_t)8 * 16 * 1024 * 64 * 2;  // 16.78 MB each
  char* ws = (char*)d_ws;
  // Aliasing: Kpk reuses xb (dead after gemm1); AO reuses Kb (dead after pack).
  unsigned short* xb     = (unsigned short*)(ws);
  unsigned short* wqkvT  = (unsigned short*)(ws + SZ_XB);
  unsigned short* wprojT = (unsigned short*)(ws + SZ_XB + SZ_WQ);
  unsigned short* Qb     = (unsigned short*)(ws + SZ_XB + SZ_WQ + SZ_WP);
  unsigned short* Kb     = (unsigned short*)(ws + SZ_XB + SZ_WQ + SZ_WP + SZ_QKV);
  unsigned short* Vraw   = (unsigned short*)(ws + SZ_XB + SZ_WQ + SZ_WP + 2 * SZ_QKV);
  unsigned short* Vpk    = (unsigned short*)(ws + SZ_XB + SZ_WQ + SZ_WP + 3 * SZ_QKV);
  unsigned short* Kpk    = xb;     // alias
  unsigned short* AOb    = Kb;     // alias
  size_t needed = SZ_XB + SZ_WQ + SZ_WP + 4 * SZ_QKV;        // ~92.3 MB
  if (ws_size < needed) return;

  k_cvt<<<8192, 256, 0, stream>>>(x, xb, 8192 * 1024 / 4);
  dim3 tb(32, 8);
  k_tr_cvt<<<dim3(96, 32), tb, 0, stream>>>(w_qkv, wqkvT, 1024, 3072);
  k_tr_cvt<<<dim3(32, 32), tb, 0, stream>>>(w_proj, wprojT, 1024, 1024);
  // QKV GEMM -> Q(scaled), K, Vraw [B,H,N,D]
  k_gemm1<<<384, 512, 0, stream>>>(xb, wqkvT, b_qkv, Qb, Kb, Vraw);
  // pack K,V fragment-major (xb dead -> Kpk aliases it)
  k_pack<<<dim3(16, 128), 256, 0, stream>>>(Kb, Vraw, Kpk, Vpk);
  // barrier-free attention -> AO (aliases Kb)
  k_attn<<<dim3(128, 8), 256, 0, stream>>>(Qb, Kpk, Vpk, AOb);
  // projection -> out fp32
  k_gemm<2, 1024><<<64 * 8, 256, 0, stream>>>(AOb, wprojT, b_proj, out);
}

// Round 8
// 240.090 us; speedup vs baseline: 1.0422x; 1.0314x over previous
//
#include <hip/hip_runtime.h>
#include <stdint.h>
#include <stddef.h>

// Multi-head attention: x@w_qkv+b -> heads -> softmax(QK^T/sqrt(D))V -> @w_proj+b
// B=8 N=1024 C=1024 H=16 D=64. bf16 MFMA, fp32 accum, fp32 softmax (log2 domain).
// GEMM1: m97 128x128 (measured best at this shape); V written TRANSPOSED in epilogue
// (deletes the k_tr_v pass). Attention: 32x32x16 swapped MFMA, LDS double-buffered.

#define DEVI __device__ __forceinline__

typedef float f32x4 __attribute__((ext_vector_type(4)));
typedef float f32x16 __attribute__((ext_vector_type(16)));
typedef __bf16 bf16x8 __attribute__((ext_vector_type(8)));
typedef unsigned short u16x8 __attribute__((ext_vector_type(8)));
typedef unsigned short u16x4 __attribute__((ext_vector_type(4)));
typedef unsigned int u32;
typedef unsigned int u32x4 __attribute__((ext_vector_type(4)));

static constexpr int M1 = 8192;   // B*N rows

DEVI unsigned short f2bf(float f) {
  uint32_t u = __builtin_bit_cast(uint32_t, f);
  u += 0x7FFFu + ((u >> 16) & 1u);   // RNE
  return (unsigned short)(u >> 16);
}

DEVI float fexp2(float x) {
  float r;
  asm("v_exp_f32 %0, %1" : "=v"(r) : "v"(x));
  return r;
}

DEVI u32 cvtpk(float lo, float hi) {
  u32 r;
  asm("v_cvt_pk_bf16_f32 %0, %1, %2" : "=v"(r) : "v"(lo), "v"(hi));
  return r;
}

DEVI void plswap(u32& a, u32& b) {
  asm("v_permlane32_swap_b32 %0, %1" : "+v"(a), "+v"(b));
}

DEVI void gll16(const unsigned short* g, unsigned short* lds) {
  __builtin_amdgcn_global_load_lds(
      (const __attribute__((address_space(1))) void*)g,
      (__attribute__((address_space(3))) void*)lds, 16, 0, 0);
}

DEVI bf16x8 lds_frag(const unsigned short* p) {
  return __builtin_bit_cast(bf16x8, *(const u16x8*)p);
}

// ---------------- convert x fp32 -> bf16 ----------------
__global__ void k_cvt(const float* __restrict__ in, unsigned short* __restrict__ out, int n4) {
  int i = blockIdx.x * blockDim.x + threadIdx.x;
  if (i < n4) {
    float4 v = reinterpret_cast<const float4*>(in)[i];
    u16x4 o = { f2bf(v.x), f2bf(v.y), f2bf(v.z), f2bf(v.w) };
    reinterpret_cast<u16x4*>(out)[i] = o;
  }
}

// ---------------- transpose + convert weights: in[R][C] fp32 -> out[C][R] bf16 ----------------
__global__ void k_tr_cvt(const float* __restrict__ in, unsigned short* __restrict__ out,
                         int R, int Cc) {
  __shared__ float tile[32][33];
  int c0 = blockIdx.x * 32, r0 = blockIdx.y * 32;
  int tx = threadIdx.x, ty = threadIdx.y;   // blockDim (32,8)
#pragma unroll
  for (int j = 0; j < 32; j += 8)
    tile[ty + j][tx] = in[(size_t)(r0 + ty + j) * Cc + c0 + tx];
  __syncthreads();
#pragma unroll
  for (int j = 0; j < 32; j += 8)
    out[(size_t)(c0 + ty + j) * R + r0 + tx] = f2bf(tile[tx][ty + j]);
}

// ---------------- GEMM: C[M x NCOLS] = A[M x 1024] * Bt[NCOLS x 1024]^T ----------------
// 128x128 tile, BK=32, 4 waves each 64x64 (m97 structure).
// EPI==1: +bias -> Q (prescaled log2e/8) [B,H,N,D], K [B,H,N,D], V TRANSPOSED [B,H,D,N].
// EPI==2: +bias -> fp32 Out[M x 1024].
template <int EPI, int NCOLS>
__global__ __launch_bounds__(256, 2)
void k_gemm(const unsigned short* __restrict__ A,
            const unsigned short* __restrict__ Bt,
            const float* __restrict__ bias,
            unsigned short* __restrict__ Qp,
            unsigned short* __restrict__ Kp,
            unsigned short* __restrict__ Vtp,
            float* __restrict__ Out) {
  constexpr int K = 1024, NK = K / 32;
  __shared__ unsigned short As[2][128 * 32];
  __shared__ unsigned short Bs[2][128 * 32];

  const int tid = threadIdx.x;
  const int w = tid >> 6, l = tid & 63;
  const int ln = l & 15, kg = l >> 4;
  const int wr = w >> 1, wc = w & 1;

  const int rt = blockIdx.x % (M1 / 128);
  const int ct = blockIdx.x / (M1 / 128);
  const int row0 = rt * 128, col0 = ct * 128;

  f32x4 acc[4][4] = {};

  const unsigned short* Ag = A + (size_t)row0 * K;
  const unsigned short* Bg = Bt + (size_t)col0 * K;

  auto stage = [&](int buf, int kt) {
    const unsigned short* ga = Ag + kt * 32;
    const unsigned short* gb = Bg + kt * 32;
#pragma unroll
    for (int j = 0; j < 2; j++) {
      int c = j * 256 + w * 64 + l;
      int r = c >> 2, s = c & 3;
      int ss = s ^ ((r >> 1) & 3);
      gll16(ga + (size_t)r * K + ss * 8, &As[buf][(j * 256 + w * 64) * 8]);
      gll16(gb + (size_t)r * K + ss * 8, &Bs[buf][(j * 256 + w * 64) * 8]);
    }
  };

  stage(0, 0);
  __syncthreads();

  int buf = 0;
  for (int kt = 0; kt < NK; kt++) {
    if (kt + 1 < NK) stage(buf ^ 1, kt + 1);

    bf16x8 af[4], bfr[4];
#pragma unroll
    for (int m = 0; m < 4; m++) {
      int r = wr * 64 + m * 16 + ln;
      int sl = kg ^ ((r >> 1) & 3);
      af[m] = lds_frag(&As[buf][r * 32 + sl * 8]);
    }
#pragma unroll
    for (int n = 0; n < 4; n++) {
      int r = wc * 64 + n * 16 + ln;
      int sl = kg ^ ((r >> 1) & 3);
      bfr[n] = lds_frag(&Bs[buf][r * 32 + sl * 8]);
    }
    __builtin_amdgcn_s_setprio(1);
#pragma unroll
    for (int m = 0; m < 4; m++)
#pragma unroll
      for (int n = 0; n < 4; n++)
        acc[m][n] = __builtin_amdgcn_mfma_f32_16x16x32_bf16(af[m], bfr[n], acc[m][n], 0, 0, 0);
    __builtin_amdgcn_s_setprio(0);

    __syncthreads();
    buf ^= 1;
  }

  constexpr float QS = 0.18033688011112042f;   // log2(e)/8
  float bv[4];
#pragma unroll
  for (int n = 0; n < 4; n++) bv[n] = bias[col0 + wc * 64 + n * 16 + ln];

  if constexpr (EPI == 1) {
    const int three = col0 >> 10;               // which tensor (Q/K/V)
    const int h = ((col0 & 1023) >> 6) + wc;    // head (64 cols per wave = one head)
    if (three < 2) {
      unsigned short* tgt = (three == 0) ? Qp : Kp;
      const float sc = (three == 0) ? QS : 1.f;
#pragma unroll
      for (int m = 0; m < 4; m++)
#pragma unroll
        for (int r = 0; r < 4; r++) {
          int row = row0 + wr * 64 + m * 16 + kg * 4 + r;
          int bb = row >> 10, nn = row & 1023;
          size_t base = ((size_t)(bb * 16 + h) * 1024 + nn) * 64;
#pragma unroll
          for (int n = 0; n < 4; n++)
            tgt[base + n * 16 + ln] = f2bf((acc[m][n][r] + bv[n]) * sc);
        }
    } else {
      // V: write transposed -> Vt[bh][d][n]. For fixed d each 128B line (64 nn)
      // is fully dirtied by temporally-adjacent stores of this wave -> L2 merges.
#pragma unroll
      for (int m = 0; m < 4; m++)
#pragma unroll
        for (int r = 0; r < 4; r++) {
          int row = row0 + wr * 64 + m * 16 + kg * 4 + r;
          int bb = row >> 10, nn = row & 1023;
          size_t dbase = (size_t)(bb * 16 + h) * 64;
#pragma unroll
          for (int n = 0; n < 4; n++)
            Vtp[(dbase + n * 16 + ln) * 1024 + nn] = f2bf(acc[m][n][r] + bv[n]);
        }
    }
  } else {
#pragma unroll
    for (int m = 0; m < 4; m++)
#pragma unroll
      for (int r = 0; r < 4; r++) {
        int row = row0 + wr * 64 + m * 16 + kg * 4 + r;
#pragma unroll
        for (int n = 0; n < 4; n++)
          Out[(size_t)row * 1024 + col0 + wc * 64 + n * 16 + ln] = acc[m][n][r] + bv[n];
      }
  }
}

// ---------------- flash attention, 32x32x16 swapped MFMA (round-5 best) ----------------
// grid (128 bh, 8 q-tiles); 4 waves x 32 q-rows, KVBLK=64, LDS double-buffered.
__global__ __launch_bounds__(256, 4)
void k_attn(const unsigned short* __restrict__ Qg, const unsigned short* __restrict__ Kg,
            const unsigned short* __restrict__ Vtg, unsigned short* __restrict__ AO) {
  __shared__ unsigned short Ks[2][64 * 64];
  __shared__ unsigned short Vs[2][64 * 64];

  const int tid = threadIdx.x;
  const int w = tid >> 6, l = tid & 63;
  const int lq = l & 31, b = l >> 5;

  const int bh = blockIdx.x;
  const int qt = blockIdx.y;
  const int qbase = qt * 128 + w * 32;

  bf16x8 qf[4];
#pragma unroll
  for (int kk = 0; kk < 4; kk++) {
    size_t off = ((size_t)bh * 1024 + qbase + lq) * 64 + kk * 16 + b * 8;
    qf[kk] = __builtin_bit_cast(bf16x8, *(const u16x8*)(Qg + off));
  }

  f32x16 acc[2] = {};
  float mrun = -1e30f, lrun = 0.f;

  const unsigned short* Kbh = Kg + (size_t)bh * 1024 * 64;
  const unsigned short* Vbh = Vtg + (size_t)bh * 64 * 1024;

  auto stage = [&](int buf, int t) {
#pragma unroll
    for (int j = 0; j < 2; j++) {
      int c = j * 256 + w * 64 + l;
      int r = c >> 3, s = c & 7;
      int ss = s ^ (r & 7);
      gll16(Kbh + (size_t)(t * 64 + r) * 64 + ss * 8, &Ks[buf][(j * 256 + w * 64) * 8]);
      gll16(Vbh + (size_t)r * 1024 + t * 64 + ss * 8, &Vs[buf][(j * 256 + w * 64) * 8]);
    }
  };

  stage(0, 0);
  __syncthreads();

  int buf = 0;
  for (int t = 0; t < 16; t++) {
    if (t + 1 < 16) stage(buf ^ 1, t + 1);

    f32x16 s[2];
    __builtin_amdgcn_s_setprio(1);
#pragma unroll
    for (int kb = 0; kb < 2; kb++) {
      f32x16 z = {};
#pragma unroll
      for (int kk = 0; kk < 4; kk++) {
        int row = kb * 32 + lq;
        int ss = (kk * 2 + b) ^ (row & 7);
        bf16x8 kf = lds_frag(&Ks[buf][row * 64 + ss * 8]);
        z = __builtin_amdgcn_mfma_f32_32x32x16_bf16(kf, qf[kk], z, 0, 0, 0);
      }
      s[kb] = z;
    }
    __builtin_amdgcn_s_setprio(0);

    float tm = s[0][0];
#pragma unroll
    for (int kb = 0; kb < 2; kb++)
#pragma unroll
      for (int r = 0; r < 16; r++) tm = fmaxf(tm, s[kb][r]);
    tm = fmaxf(tm, __shfl_xor(tm, 32));

    if (!__all(tm <= mrun + 8.f)) {
      float mnew = fmaxf(mrun, tm);
      float al = fexp2(mrun - mnew);
      mrun = mnew;
      lrun *= al;
#pragma unroll
      for (int r = 0; r < 16; r++) {
        float aq = __shfl(al, (r & 3) + 8 * (r >> 2) + 4 * b);
        acc[0][r] *= aq;
        acc[1][r] *= aq;
      }
    }

    float rs = 0.f;
#pragma unroll
    for (int kb = 0; kb < 2; kb++)
#pragma unroll
      for (int r = 0; r < 16; r++) {
        float pv = fexp2(s[kb][r] - mrun);
        s[kb][r] = pv;
        rs += pv;
      }
    rs += __shfl_xor(rs, 32);
    lrun += rs;

    bf16x8 pa[4];
#pragma unroll
    for (int kb = 0; kb < 2; kb++) {
      u32 pk[4][2];
#pragma unroll
      for (int t4 = 0; t4 < 4; t4++) {
        pk[t4][0] = cvtpk(s[kb][t4 * 4 + 0], s[kb][t4 * 4 + 1]);
        pk[t4][1] = cvtpk(s[kb][t4 * 4 + 2], s[kb][t4 * 4 + 3]);
      }
#pragma unroll
      for (int sh = 0; sh < 2; sh++) {
        u32 a0 = pk[2 * sh][0], b0 = pk[2 * sh + 1][0];
        plswap(a0, b0);
        u32 a1 = pk[2 * sh][1], b1 = pk[2 * sh + 1][1];
        plswap(a1, b1);
        u32x4 fr = { a0, a1, b0, b1 };
        pa[kb * 2 + sh] = __builtin_bit_cast(bf16x8, fr);
      }
    }

    __builtin_amdgcn_s_setprio(1);
#pragma unroll
    for (int n = 0; n < 2; n++) {
#pragma unroll
      for (int st = 0; st < 4; st++) {
        int row = n * 32 + lq;
        int ss = (st * 2 + b) ^ (row & 7);
        bf16x8 vb = lds_frag(&Vs[buf][row * 64 + ss * 8]);
        acc[n] = __builtin_amdgcn_mfma_f32_32x32x16_bf16(pa[st], vb, acc[n], 0, 0, 0);
      }
    }
    __builtin_amdgcn_s_setprio(0);

    __syncthreads();
    buf ^= 1;
  }

  const int bb = bh >> 4, h = bh & 15;
  float linv = 1.f / lrun;
#pragma unroll
  for (int r = 0; r < 16; r++) {
    float lq_r = __shfl(linv, (r & 3) + 8 * (r >> 2) + 4 * b);
    int row = qbase + (r & 3) + 8 * (r >> 2) + 4 * b;
    size_t base = ((size_t)(bb * 1024 + row)) * 1024 + h * 64;
#pragma unroll
    for (int n = 0; n < 2; n++)
      AO[base + n * 32 + lq] = f2bf(acc[n][r] * lq_r);
  }
}

// ---------------- launch ----------------
extern "C" void kernel_launch(void* const* d_in, const int* in_sizes, int n_in,
                              void* d_out, int out_size, void* d_ws, size_t ws_size,
                              hipStream_t stream) {
  const float* x      = (const float*)d_in[0];
  const float* w_qkv  = (const float*)d_in[1];
  const float* b_qkv  = (const float*)d_in[2];
  const float* w_proj = (const float*)d_in[3];
  const float* b_proj = (const float*)d_in[4];
  float* out = (float*)d_out;

  constexpr size_t SZ_XB  = (size_t)8192 * 1024 * 2;
  constexpr size_t SZ_WQ  = (size_t)3072 * 1024 * 2;
  constexpr size_t SZ_WP  = (size_t)1024 * 1024 * 2;
  constexpr size_t SZ_QKV = (size_t)8 * 16 * 1024 * 64 * 2;
  char* ws = (char*)d_ws;
  unsigned short* xb     = (unsigned short*)(ws);
  unsigned short* wqkvT  = (unsigned short*)(ws + SZ_XB);
  unsigned short* wprojT = (unsigned short*)(ws + SZ_XB + SZ_WQ);
  unsigned short* Qb     = (unsigned short*)(ws + SZ_XB + SZ_WQ + SZ_WP);
  unsigned short* Kb     = (unsigned short*)(ws + SZ_XB + SZ_WQ + SZ_WP + SZ_QKV);
  unsigned short* Vtb    = (unsigned short*)(ws + SZ_XB + SZ_WQ + SZ_WP + 2 * SZ_QKV);
  unsigned short* AOb    = (unsigned short*)(ws + SZ_XB + SZ_WQ + SZ_WP + 3 * SZ_QKV);
  size_t needed = SZ_XB + SZ_WQ + SZ_WP + 4 * SZ_QKV;   // ~92.3 MB
  if (ws_size < needed) return;

  k_cvt<<<8192, 256, 0, stream>>>(x, xb, 8192 * 1024 / 4);
  dim3 tb(32, 8);
  k_tr_cvt<<<dim3(96, 32), tb, 0, stream>>>(w_qkv, wqkvT, 1024, 3072);
  k_tr_cvt<<<dim3(32, 32), tb, 0, stream>>>(w_proj, wprojT, 1024, 1024);
  // QKV GEMM -> Q(scaled), K [B,H,N,D]; V written transposed -> Vt [B,H,D,N]
  k_gemm<1, 3072><<<64 * 24, 256, 0, stream>>>(xb, wqkvT, b_qkv, Qb, Kb, Vtb, nullptr);
  // flash attention -> AO
  k_attn<<<dim3(128, 8), 256, 0, stream>>>(Qb, Kb, Vtb, AOb);
  // projection -> out fp32
  k_gemm<2, 1024><<<64 * 8, 256, 0, stream>>>(AOb, wprojT, b_proj, nullptr, nullptr, nullptr, out);
}